// Round 1
// baseline (16.038 us; speedup 1.0000x reference)
//
#include <hip/hip_runtime.h>

// SurfEval: NURBS surface evaluation.
// ctrl_pts: (B=4, M=128, N=128, 4) f32  -> treated as float4 grid (B,M,N)
// Nu: (1024,4) f32, Nv: (1024,4) f32, uspan: (1024,) i32, vspan: (1024,) i32
// out: (B,1024,1024,3) f32
//
// Per block: one (b,u) row. Stage tu[j] = sum_l Nu[u,l]*ctrl[b,us-3+l,j]
// into LDS (128 x float4 = 2KB), then each thread computes 4 v-points:
// sw = sum_r Nv[v,r]*tu[vs-3+r]; out = sw.xyz / sw.w.

#define OUT_U 1024
#define OUT_V 1024
#define MCTRL 128
#define NCTRL 128

__device__ __forceinline__ void fma4(float4& acc, float w, const float4& a) {
    acc.x = fmaf(w, a.x, acc.x);
    acc.y = fmaf(w, a.y, acc.y);
    acc.z = fmaf(w, a.z, acc.z);
    acc.w = fmaf(w, a.w, acc.w);
}

__global__ __launch_bounds__(256) void surf_eval_kernel(
    const float4* __restrict__ ctrl,   // (B,M,N)
    const float4* __restrict__ Nu,     // (OUT_U)
    const float4* __restrict__ Nv,     // (OUT_V)
    const int*    __restrict__ uspan,  // (OUT_U)
    const int*    __restrict__ vspan,  // (OUT_V)
    float*        __restrict__ out)    // (B,OUT_U,OUT_V,3)
{
    __shared__ float4 tu[NCTRL];

    const int bu  = blockIdx.x;        // b*1024 + u
    const int b   = bu >> 10;
    const int u   = bu & 1023;
    const int tid = threadIdx.x;

    const int   us = uspan[u];         // in [3,127]
    const float4 nu = Nu[u];

    // Stage 1: u-contraction into LDS (threads 0..127)
    if (tid < NCTRL) {
        const float4* row = ctrl + ((size_t)(b * MCTRL + (us - 3)) * NCTRL) + tid;
        float4 a0 = row[0];
        float4 a1 = row[NCTRL];
        float4 a2 = row[2 * NCTRL];
        float4 a3 = row[3 * NCTRL];
        float4 acc;
        acc.x = nu.x * a0.x; acc.y = nu.x * a0.y;
        acc.z = nu.x * a0.z; acc.w = nu.x * a0.w;
        fma4(acc, nu.y, a1);
        fma4(acc, nu.z, a2);
        fma4(acc, nu.w, a3);
        tu[tid] = acc;
    }
    __syncthreads();

    // Stage 2: v-contraction, 4 points per thread
    const size_t outrow = (size_t)bu * OUT_V;
#pragma unroll
    for (int k = 0; k < 4; ++k) {
        const int v  = tid + k * 256;
        const int vs = vspan[v];       // in [3,127]
        const float4 nv = Nv[v];

        const float4 t0 = tu[vs - 3];
        const float4 t1 = tu[vs - 2];
        const float4 t2 = tu[vs - 1];
        const float4 t3 = tu[vs];

        float4 acc;
        acc.x = nv.x * t0.x; acc.y = nv.x * t0.y;
        acc.z = nv.x * t0.z; acc.w = nv.x * t0.w;
        fma4(acc, nv.y, t1);
        fma4(acc, nv.z, t2);
        fma4(acc, nv.w, t3);

        const float inv = 1.0f / acc.w;
        const size_t o = (outrow + (size_t)v) * 3;
        out[o + 0] = acc.x * inv;
        out[o + 1] = acc.y * inv;
        out[o + 2] = acc.z * inv;
    }
}

extern "C" void kernel_launch(void* const* d_in, const int* in_sizes, int n_in,
                              void* d_out, int out_size, void* d_ws, size_t ws_size,
                              hipStream_t stream) {
    const float4* ctrl  = (const float4*)d_in[0];
    const float4* Nu    = (const float4*)d_in[1];
    const float4* Nv    = (const float4*)d_in[2];
    const int*    uspan = (const int*)d_in[3];
    const int*    vspan = (const int*)d_in[4];
    float*        out   = (float*)d_out;

    const int nblocks = 4 * OUT_U; // one block per (b,u) row
    surf_eval_kernel<<<nblocks, 256, 0, stream>>>(ctrl, Nu, Nv, uspan, vspan, out);
}